// Round 13
// baseline (266.338 us; speedup 1.0000x reference)
//
#include <hip/hip_runtime.h>
#include <math.h>

// ---------------------------------------------------------------------------
// Quantized CNN forward (bitwise-exact vs fp32 reference):
//   block_k: maxpool2( quant_act( conv3x3(x, quant_weight(wk)), ak ) )
//   then global max over HxW, then 1x1 conv (10x128).
//
// R27: R26 = 250.1us (best). conv2 at 75us is ~70% latency-stalled (VALU
// 31%, LDS ~45% incl conflicts which R19 proved non-critical). True register
// footprint ~120/wave (VGPR_Count 56 excludes the 64 acc regs in AGPR space
// of the unified file) -> 16-wave/CU cap (m69 thresholds 64/128/256),
// measured ~11.5. This round halves per-thread state to cross the 64-reg
// threshold: 8-co groups (acc 32) + 2-channel chunks (v 10) +
// launch_bounds(256,8) -> ~60-64 regs -> 32-wave cap (2-2.8x residency).
// Cost: staging total x2, barriers x2 (~+60% issue) -- wins iff the stall
// fraction collapses. Prefetch issued AFTER sync2 (R23-verified placement:
// loads age through compute, not drained at sync2). conv1 (GW=16 path),
// prep, classify, fused-gmax: R26-verified code, parameterized. Per-acc
// order (chunk asc, cil asc, k asc) unchanged -> bitwise-same.
// Pre-commit: flat/regressed w/ VGPR<=64 & no spill -> R26 is the plateau.
// ---------------------------------------------------------------------------

__global__ __launch_bounds__(256)
void prep_zero(unsigned* __restrict__ maxb, float* __restrict__ g) {
    const int i = blockIdx.x * 256 + threadIdx.x;
    if (i < 4) maxb[i] = 0u;
    if (i < 4096) g[i] = 0.f;                     // all outputs >= 0
}

__global__ __launch_bounds__(256)
void prep_absmax(const float* __restrict__ w1, const float* __restrict__ w2,
                 const float* __restrict__ w3, const float* __restrict__ wc,
                 unsigned* __restrict__ maxb) {
    const float* srcs[4] = {w1, w2, w3, wc};
    const int    ns[4]   = {32*3*9, 64*32*9, 128*64*9, 10*128};
    const int t = blockIdx.y;
    const float* s = srcs[t];
    const int    N = ns[t];
    float m = 0.f;
    for (int i = blockIdx.x * 256 + threadIdx.x; i < N; i += 16 * 256)
        m = fmaxf(m, fabsf(s[i]));
    #pragma unroll
    for (int o = 32; o > 0; o >>= 1) m = fmaxf(m, __shfl_down(m, o));
    __shared__ float red[4];
    const int lane = threadIdx.x & 63, wid = threadIdx.x >> 6;
    if (lane == 0) red[wid] = m;
    __syncthreads();
    if (threadIdx.x == 0) {
        float mm = fmaxf(fmaxf(red[0], red[1]), fmaxf(red[2], red[3]));
        atomicMax(maxb + t, __float_as_uint(mm));  // |w|>=0: uint order == float order
    }
}

// Classifier weights still need real quantized values (ternary * s).
__global__ __launch_bounds__(256)
void prep_qwc(const float* __restrict__ wc, const unsigned* __restrict__ maxb,
              float* __restrict__ qwc) {
    const float sc = fmaxf(__uint_as_float(maxb[3]), 1e-8f);
    const int i = blockIdx.x * 256 + threadIdx.x;
    if (i < 1280) qwc[i] = rintf(wc[i] / sc) * sc;
}

// Compacted nz-tap lists, grp width GW (16 for conv1, 8 for conv2/3).
// Per (grp-of-GW-co, ci-chunk-of-CCH) a header of GW/4 + 2*GW dwords:
// first GW/4 dwords = GW u8 counts; then per-co 4 inline u16 entries.
// Entry = sign<<15 | word_off, word_off = cil*1156 + (k/3)*34 + (k%3).
// Entries j>=4 -> pool[(rc*GW + c)*32 + (j-4)] (cap 32; max 27-4=23).
// Order within a co: chunk asc, cil asc, k asc == global (ci asc, k asc).
__global__ __launch_bounds__(256)
void build_lists(const float* __restrict__ w1, const float* __restrict__ w2,
                 const float* __restrict__ w3, const unsigned* __restrict__ maxb,
                 unsigned* __restrict__ h1, unsigned short* __restrict__ p1,
                 unsigned* __restrict__ h2, unsigned short* __restrict__ p2,
                 unsigned* __restrict__ h3, unsigned short* __restrict__ p3) {
    const float* wsrc[3] = {w1, w2, w3};
    unsigned*       hs[3] = {h1, h2, h3};
    unsigned short* ps[3] = {p1, p2, p3};
    const int cins[3] = {3, 32, 64};
    const int cchs[3] = {3, 2, 2};
    const int nch[3]  = {1, 16, 32};
    const int gws[3]  = {16, 8, 8};
    const int rcs[3]  = {2, 128, 512};      // (Co/GW) * NCHUNK
    const int t = blockIdx.y;
    const float* w = wsrc[t];
    const int CIN = cins[t], CCH = cchs[t], NCHUNK = nch[t], GW = gws[t];
    const int HDW = GW / 4 + 2 * GW;
    const int total = rcs[t] * GW;
    const float sc = fmaxf(__uint_as_float(maxb[t]), 1e-8f);
    for (int u = blockIdx.x * 256 + threadIdx.x; u < total; u += 8 * 256) {
        const int c = u % GW, rc = u / GW;  // rc = grp*NCHUNK + ch
        const int ch = rc % NCHUNK, grp = rc / NCHUNK;
        const int co = grp * GW + c;
        unsigned* hdr = hs[t] + (size_t)rc * HDW;
        unsigned short* inl = (unsigned short*)(hdr + GW / 4);
        unsigned short* ovf = ps[t] + ((size_t)rc * GW + c) * 32;
        int j = 0;
        for (int cil = 0; cil < CCH; ++cil) {
            const int ci = ch * CCH + cil;
            if (ci >= CIN) break;
            for (int k = 0; k < 9; ++k) {
                const float q = rintf(w[(co * CIN + ci) * 9 + k] / sc);
                unsigned sgn;
                if (q > 0.5f)       sgn = 0u;
                else if (q < -0.5f) sgn = 0x8000u;
                else continue;
                const unsigned off = (unsigned)(cil * 1156 + (k / 3) * 34 + (k % 3));
                const unsigned short e = (unsigned short)(sgn | off);
                if (j < 4) inl[c * 4 + j] = e;
                else       ovf[j - 4] = e;
                ++j;
            }
        }
        ((unsigned char*)hdr)[c] = (unsigned char)j;
    }
}

// Sparse fused conv3x3(pad=1) + maxpool2 + quant_act.
// 16x16 threads over a 16x16 pooled tile (32x32 conv px, 34x34 input tile).
// GW co per block; ci in chunks of CCHp; staging reg-pipelined; prefetch
// issued AFTER sync2 (ages through the compute phase, not drained).
// LIDX==2: fused global-max epilogue (atomicMax into pre-zeroed g).
template<int CIN, int Co, int LIDX, int GW, int CCHp, int MINW>
__global__ __launch_bounds__(256, MINW)
void conv_sparse(const float* __restrict__ in, const unsigned* __restrict__ hdrs,
                 const unsigned short* __restrict__ pool,
                 const unsigned* __restrict__ maxb,
                 const float* __restrict__ alpha_p, float* __restrict__ out,
                 int H, int W) {
    constexpr int CCH    = (CIN < CCHp) ? CIN : CCHp;
    constexpr int NCHUNK = (CIN + CCH - 1) / CCH;
    constexpr int NGRP   = Co / GW;
    constexpr int HDW    = GW / 4 + 2 * GW;
    const int PH = H >> 1, PW = W >> 1;
    const int tx = threadIdx.x, ty = threadIdx.y;
    const int tid = ty * 16 + tx;
    const int b   = blockIdx.z / NGRP;
    const int grp = blockIdx.z % NGRP;
    const int px  = blockIdx.x * 16 + tx;
    const int py  = blockIdx.y * 16 + ty;
    const int ix0 = blockIdx.x * 32 - 1;
    const int iy0 = blockIdx.y * 32 - 1;

    __shared__ float tile[CCH * 1156];           // chunk-local [cil][34*34] flat
    const size_t HW = (size_t)H * W;
    const float* inB = in + (size_t)b * CIN * HW;

    // Flat staging slots hoisted once; -1 = zero-fill (pad / out of image).
    int sidx[5];
    #pragma unroll
    for (int s = 0; s < 5; ++s) {
        const int idx = tid + 256 * s;
        const int r = idx / 34, c = idx - r * 34;
        const int gy = iy0 + r, gx = ix0 + c;
        sidx[s] = (idx < 1156 && gy >= 0 && gy < H && gx >= 0 && gx < W)
                  ? (gy * W + gx) : -1;
    }

    float v[CCH][5];                              // in-flight staging buffer
    auto load_chunk = [&](int ch0) {
        #pragma unroll
        for (int ch = 0; ch < CCH; ++ch) {
            const float* inC = inB + (size_t)(ch0 + ch) * HW;
            #pragma unroll
            for (int s = 0; s < 5; ++s)
                v[ch][s] = (sidx[s] >= 0) ? inC[sidx[s]] : 0.f;
        }
    };
    auto store_tile = [&]() {
        #pragma unroll
        for (int ch = 0; ch < CCH; ++ch)
            #pragma unroll
            for (int s = 0; s < 5; ++s) {
                const int idx = tid + 256 * s;    // imm-offset ds_write
                if (s < 4 || idx < 1156) tile[ch * 1156 + idx] = v[ch][s];
            }
    };

    // +-s in SGPRs: exact (s = fmax(absmax,1e-8); -s = exact sign flip).
    const float sAbs = fmaxf(__uint_as_float(maxb[LIDX]), 1e-8f);
    const float sPos = __uint_as_float(__builtin_amdgcn_readfirstlane(__float_as_uint(sAbs)));
    const float sNeg = __uint_as_float(__builtin_amdgcn_readfirstlane(__float_as_uint(-sAbs)));

    float acc[GW][4];
    #pragma unroll
    for (int c = 0; c < GW; ++c)
        #pragma unroll
        for (int q = 0; q < 4; ++q) acc[c][q] = 0.f;

    const int base = (2 * ty) * 34 + 2 * tx;     // lane's patch origin (words)

    load_chunk(0);                                // prologue

    #pragma unroll 1
    for (int chunk = 0; chunk < NCHUNK; ++chunk) {
        // Header loads issued first: uniform s_load; ages under store+syncs.
        const unsigned* hdr = hdrs + (size_t)(grp * NCHUNK + chunk) * HDW;
        unsigned cntd[GW / 4];
        #pragma unroll
        for (int i = 0; i < GW / 4; ++i) cntd[i] = hdr[i];
        unsigned ent[2 * GW];
        #pragma unroll
        for (int i = 0; i < 2 * GW; ++i) ent[i] = hdr[GW / 4 + i];

        __syncthreads();                          // sync1: tile free (drains
                                                  // prev prefetch, now aged)
        store_tile();                             // v -> tile
        __syncthreads();                          // sync2: writes visible
        if (chunk + 1 < NCHUNK) load_chunk((chunk + 1) * CCH);
        // ^ issued AFTER sync2: ages through the whole compute phase.

        const float* tb = tile + base;

        #pragma unroll
        for (int c = 0; c < GW; ++c) {
            const unsigned cnt = (cntd[c >> 2] >> ((c & 3) * 8)) & 0xffu;
            if (!cnt) continue;                   // uniform skip
            #pragma unroll
            for (int j = 0; j < 4; ++j) {
                if ((int)cnt > j) {
                    const unsigned e = (ent[2 * c + (j >> 1)] >> ((j & 1) * 16)) & 0xffffu;
                    const float wv = (e & 0x8000u) ? sNeg : sPos;   // s_cselect
                    const float* q = tb + (e & 0x7fffu);            // v_add
                    acc[c][0] = fmaf(wv, q[0],  acc[c][0]);
                    acc[c][1] = fmaf(wv, q[1],  acc[c][1]);
                    acc[c][2] = fmaf(wv, q[34], acc[c][2]);
                    acc[c][3] = fmaf(wv, q[35], acc[c][3]);
                }
            }
            if (cnt > 4) {                        // rare
                const unsigned short* pp =
                    pool + ((size_t)(grp * NCHUNK + chunk) * GW + c) * 32;
                #pragma unroll 1
                for (int j = 4; j < (int)cnt; ++j) {
                    const unsigned e = pp[j - 4];
                    const float wv = (e & 0x8000u) ? sNeg : sPos;
                    const float* q = tb + (e & 0x7fffu);
                    acc[c][0] = fmaf(wv, q[0],  acc[c][0]);
                    acc[c][1] = fmaf(wv, q[1],  acc[c][1]);
                    acc[c][2] = fmaf(wv, q[34], acc[c][2]);
                    acc[c][3] = fmaf(wv, q[35], acc[c][3]);
                }
            }
        }
    }

    if constexpr (LIDX == 2) {
        // Fused global-max epilogue: out == g[32][128]. Values >= 0; max is
        // order-independent bit-exact; invalid threads contribute 0.0.
        const float alpha = *alpha_p;
        const float scale = alpha / 3.0f;         // 2^ABITS - 1 = 3
        const bool valid = (py < PH) && (px < PW);
        float mv[GW];
        #pragma unroll
        for (int c = 0; c < GW; ++c) {
            const float m = fmaxf(fmaxf(acc[c][0], acc[c][1]),
                                  fmaxf(acc[c][2], acc[c][3]));
            const float y = fminf(fmaxf(m, 0.f), alpha);
            const float q = rintf(y / scale) * scale;
            mv[c] = valid ? q : 0.f;
        }
        #pragma unroll
        for (int c = 0; c < GW; ++c)
            #pragma unroll
            for (int o = 32; o > 0; o >>= 1)
                mv[c] = fmaxf(mv[c], __shfl_down(mv[c], o));
        __shared__ float red[4][GW];
        const int lane = tid & 63, wv = tid >> 6;
        if (lane == 0) {
            #pragma unroll
            for (int c = 0; c < GW; ++c) red[wv][c] = mv[c];
        }
        __syncthreads();
        if (tid < GW) {
            const float r = fmaxf(fmaxf(red[0][tid], red[1][tid]),
                                  fmaxf(red[2][tid], red[3][tid]));
            atomicMax((unsigned*)(out + (size_t)b * 128 + grp * GW + tid),
                      __float_as_uint(r));        // >=0: uint order == float
        }
    } else if (py < PH && px < PW) {
        const float alpha = *alpha_p;
        const float scale = alpha / 3.0f;         // 2^ABITS - 1 = 3
        #pragma unroll
        for (int c = 0; c < GW; ++c) {
            const float m = fmaxf(fmaxf(acc[c][0], acc[c][1]),
                                  fmaxf(acc[c][2], acc[c][3]));
            const float y = fminf(fmaxf(m, 0.f), alpha);
            out[(((size_t)b * Co + grp * GW + c) * PH + py) * PW + px] =
                rintf(y / scale) * scale;
        }
    }
}

// 1x1 conv 128->10 per batch (same k-ascending FMA order as round 1).
__global__ __launch_bounds__(128)
void classify_kernel(const float* __restrict__ g, const float* __restrict__ qwc,
                     float* __restrict__ out) {
    const int b = blockIdx.x;
    __shared__ float gg[128];
    gg[threadIdx.x] = g[b * 128 + threadIdx.x];
    __syncthreads();
    if (threadIdx.x < 10) {
        float s = 0.f;
        for (int k = 0; k < 128; ++k) s += qwc[threadIdx.x * 128 + k] * gg[k];
        out[b * 10 + threadIdx.x] = s;
    }
}

extern "C" void kernel_launch(void* const* d_in, const int* in_sizes, int n_in,
                              void* d_out, int out_size, void* d_ws, size_t ws_size,
                              hipStream_t stream) {
    const float* x  = (const float*)d_in[0];
    const float* w1 = (const float*)d_in[1];
    const float* w2 = (const float*)d_in[2];
    const float* w3 = (const float*)d_in[3];
    const float* wc = (const float*)d_in[4];
    const float* a1 = (const float*)d_in[5];
    const float* a2 = (const float*)d_in[6];
    const float* a3 = (const float*)d_in[7];

    float* ws = (float*)d_ws;
    size_t o = 0;
    float*    qwc  = ws + o; o += 1280;
    unsigned* maxb = (unsigned*)(ws + o); o += 4;
    float*    g    = ws + o; o += 32 * 128;
    unsigned*       h1 = (unsigned*)(ws + o);       o += 2   * 36;     // GW16 hdrs
    unsigned short* p1 = (unsigned short*)(ws + o); o += 512;          // 2*16*32 hw
    unsigned*       h2 = (unsigned*)(ws + o);       o += 128 * 18;     // GW8 hdrs
    unsigned short* p2 = (unsigned short*)(ws + o); o += 16384;        // 128*8*32 hw
    unsigned*       h3 = (unsigned*)(ws + o);       o += 512 * 18;
    unsigned short* p3 = (unsigned short*)(ws + o); o += 65536;        // 512*8*32 hw
    float* h1p = ws + o; o += (size_t)32 * 32 * 112 * 112;
    float* h2p = ws + o; o += (size_t)32 * 64 * 56 * 56;

    prep_zero<<<16, 256, 0, stream>>>(maxb, g);
    prep_absmax<<<dim3(16, 4), 256, 0, stream>>>(w1, w2, w3, wc, maxb);
    prep_qwc<<<5, 256, 0, stream>>>(wc, maxb, qwc);
    build_lists<<<dim3(8, 3), 256, 0, stream>>>(w1, w2, w3, maxb,
                                                h1, p1, h2, p2, h3, p3);

    // conv1: 3->32, GW=16, CCH=3 (R26-identical). tiles 7x7, z = 32b * 2 grp
    conv_sparse<3, 32, 0, 16, 3, 4><<<dim3(7, 7, 32 * 2), dim3(16, 16), 0, stream>>>(
        x, h1, p1, maxb, a1, h1p, 224, 224);
    // conv2: 32->64, GW=8, CCH=2, 32-wave target. tiles 4x4, z = 32b * 8 grp
    conv_sparse<32, 64, 1, 8, 2, 8><<<dim3(4, 4, 32 * 8), dim3(16, 16), 0, stream>>>(
        h1p, h2, p2, maxb, a2, h2p, 112, 112);
    // conv3: 64->128, GW=8, CCH=2, fused global-max -> g. z = 32b * 16 grp
    conv_sparse<64, 128, 2, 8, 2, 8><<<dim3(2, 2, 32 * 16), dim3(16, 16), 0, stream>>>(
        h2p, h3, p3, maxb, a3, g, 56, 56);

    classify_kernel<<<32, 128, 0, stream>>>(g, qwc, (float*)d_out);
}

// Round 14
// 247.052 us; speedup vs baseline: 1.0781x; 1.0781x over previous
//
#include <hip/hip_runtime.h>
#include <math.h>

// ---------------------------------------------------------------------------
// Quantized CNN forward (bitwise-exact vs fp32 reference):
//   block_k: maxpool2( quant_act( conv3x3(x, quant_weight(wk)), ak ) )
//   then global max over HxW, then 1x1 conv (10x128).
//
// R28 (final consolidation): R27 answered the occupancy question NO
// (occ 36->66%, duration 75->81.6: staging x2 cost > latency-hiding gain).
// All structural levers now tested: conflicts (R19: null), DMA (R20/21:
// regress), raw-barrier pipeline (R22: died), pair read-ahead (R23:
// regress), float2 staging (R24: regress), 8-FMA amortize (R25: regress),
// occupancy (R27: regress). R26 = 250.1us is the verified floor of this
// family. This round: R26 byte-for-byte, plus the ONE ingredient never
// isolated -- prefetch issued AFTER sync2 (loads age through the compute
// phase instead of being vmcnt(0)-drained cold at sync2; placement passed
// correctness in R23/R27) -- and prep_qwc folded into build_lists (one
// fewer launch). Pre-commit: total >= 249 -> R26 structure is the floor.
// ---------------------------------------------------------------------------

__global__ __launch_bounds__(256)
void prep_zero(unsigned* __restrict__ maxb, float* __restrict__ g) {
    const int i = blockIdx.x * 256 + threadIdx.x;
    if (i < 4) maxb[i] = 0u;
    if (i < 4096) g[i] = 0.f;                     // all outputs >= 0
}

__global__ __launch_bounds__(256)
void prep_absmax(const float* __restrict__ w1, const float* __restrict__ w2,
                 const float* __restrict__ w3, const float* __restrict__ wc,
                 unsigned* __restrict__ maxb) {
    const float* srcs[4] = {w1, w2, w3, wc};
    const int    ns[4]   = {32*3*9, 64*32*9, 128*64*9, 10*128};
    const int t = blockIdx.y;
    const float* s = srcs[t];
    const int    N = ns[t];
    float m = 0.f;
    for (int i = blockIdx.x * 256 + threadIdx.x; i < N; i += 16 * 256)
        m = fmaxf(m, fabsf(s[i]));
    #pragma unroll
    for (int o = 32; o > 0; o >>= 1) m = fmaxf(m, __shfl_down(m, o));
    __shared__ float red[4];
    const int lane = threadIdx.x & 63, wid = threadIdx.x >> 6;
    if (lane == 0) red[wid] = m;
    __syncthreads();
    if (threadIdx.x == 0) {
        float mm = fmaxf(fmaxf(red[0], red[1]), fmaxf(red[2], red[3]));
        atomicMax(maxb + t, __float_as_uint(mm));  // |w|>=0: uint order == float order
    }
}

// Compacted nz-tap lists (+ fused classifier-weight quant at t==3).
// Per (grp-of-16-co, chunk-of-4-ci) a 36-dword header: dwords 0..3 = 16 u8
// counts; dwords 4..35 = per-co 4 inline u16 entries (co c at halfwords
// 8+4c .. 8+4c+3). Entry = sign<<15 | word_off,
// word_off = cil*1156 + (k/3)*34 + (k%3)  (max 3538 < 0x8000).
// Entries j>=4 go to pool[(rc*16+c)*32 + (j-4)] (capacity 32; 4+32=36 max).
// Order within a co: cil asc, k asc == the verified accumulation order.
__global__ __launch_bounds__(256)
void build_lists(const float* __restrict__ w1, const float* __restrict__ w2,
                 const float* __restrict__ w3, const float* __restrict__ wc,
                 const unsigned* __restrict__ maxb,
                 unsigned* __restrict__ h1, unsigned short* __restrict__ p1,
                 unsigned* __restrict__ h2, unsigned short* __restrict__ p2,
                 unsigned* __restrict__ h3, unsigned short* __restrict__ p3,
                 float* __restrict__ qwc) {
    const int t = blockIdx.y;
    if (t == 3) {                                 // fused prep_qwc
        const float sc = fmaxf(__uint_as_float(maxb[3]), 1e-8f);
        const int i = blockIdx.x * 256 + threadIdx.x;
        if (i < 1280) qwc[i] = rintf(wc[i] / sc) * sc;
        return;
    }
    const float* wsrc[3] = {w1, w2, w3};
    unsigned*       hs[3] = {h1, h2, h3};
    unsigned short* ps[3] = {p1, p2, p3};
    const int cins[3] = {3, 32, 64};
    const int nch[3]  = {1, 8, 16};
    const int ngc[3]  = {2, 32, 128};       // (Co/16) * nchunk
    const float* w = wsrc[t];
    const int CIN = cins[t], NCHUNK = nch[t];
    const int total = ngc[t] * 16;
    const float sc = fmaxf(__uint_as_float(maxb[t]), 1e-8f);
    for (int u = blockIdx.x * 256 + threadIdx.x; u < total; u += 8 * 256) {
        const int c = u & 15, rc = u >> 4;  // rc = grp*NCHUNK + ch
        const int ch = rc % NCHUNK, grp = rc / NCHUNK;
        const int co = grp * 16 + c;
        unsigned* hdr = hs[t] + (size_t)rc * 36;
        unsigned short* inl = (unsigned short*)(hdr + 4);
        unsigned short* ovf = ps[t] + ((size_t)rc * 16 + c) * 32;
        int j = 0;
        for (int cil = 0; cil < 4; ++cil) {
            const int ci = ch * 4 + cil;
            if (ci >= CIN) break;
            for (int k = 0; k < 9; ++k) {
                const float q = rintf(w[(co * CIN + ci) * 9 + k] / sc);
                unsigned sgn;
                if (q > 0.5f)       sgn = 0u;
                else if (q < -0.5f) sgn = 0x8000u;
                else continue;
                const unsigned off = (unsigned)(cil * 1156 + (k / 3) * 34 + (k % 3));
                const unsigned short e = (unsigned short)(sgn | off);
                if (j < 4) inl[c * 4 + j] = e;
                else       ovf[j - 4] = e;
                ++j;
            }
        }
        ((unsigned char*)hdr)[c] = (unsigned char)j;
    }
}

// Sparse fused conv3x3(pad=1) + maxpool2 + quant_act.
// 16x16 threads over a 16x16 pooled tile (32x32 conv px, 34x34 input tile).
// ci in chunks of 4; staging reg-pipelined; prefetch issued AFTER sync2
// (ages through the compute phase; next sync1 drains landed data).
// Compute: per co, walk the compacted entry list; each entry carries its
// LDS word-offset, so the 2x2 patch values are read directly.
// LIDX==2 (conv3): epilogue reduces the block's quantized pooled values to
// per-co maxima and atomicMax's into g (no h3 tensor, no gmax kernel).
template<int CIN, int Co, int LIDX>
__global__ __launch_bounds__(256, 4)
void conv_sparse(const float* __restrict__ in, const unsigned* __restrict__ hdrs,
                 const unsigned short* __restrict__ pool,
                 const unsigned* __restrict__ maxb,
                 const float* __restrict__ alpha_p, float* __restrict__ out,
                 int H, int W) {
    constexpr int NCHUNK = (CIN + 3) / 4;
    constexpr int CCH    = (CIN < 4) ? CIN : 4;
    constexpr int NGRP   = Co / 16;
    const int PH = H >> 1, PW = W >> 1;
    const int tx = threadIdx.x, ty = threadIdx.y;
    const int tid = ty * 16 + tx;
    const int b   = blockIdx.z / NGRP;
    const int grp = blockIdx.z % NGRP;
    const int px  = blockIdx.x * 16 + tx;
    const int py  = blockIdx.y * 16 + ty;
    const int ix0 = blockIdx.x * 32 - 1;
    const int iy0 = blockIdx.y * 32 - 1;

    __shared__ float tile[CCH * 1156];           // chunk-local [cil][34*34] flat
    const size_t HW = (size_t)H * W;
    const float* inB = in + (size_t)b * CIN * HW;

    // Flat staging slots hoisted once; -1 = zero-fill (pad / out of image).
    int sidx[5];
    #pragma unroll
    for (int s = 0; s < 5; ++s) {
        const int idx = tid + 256 * s;
        const int r = idx / 34, c = idx - r * 34;
        const int gy = iy0 + r, gx = ix0 + c;
        sidx[s] = (idx < 1156 && gy >= 0 && gy < H && gx >= 0 && gx < W)
                  ? (gy * W + gx) : -1;
    }

    float v[CCH][5];                              // in-flight staging buffer
    auto load_chunk = [&](int ch0) {
        #pragma unroll
        for (int ch = 0; ch < CCH; ++ch) {
            const float* inC = inB + (size_t)(ch0 + ch) * HW;
            #pragma unroll
            for (int s = 0; s < 5; ++s)
                v[ch][s] = (sidx[s] >= 0) ? inC[sidx[s]] : 0.f;
        }
    };
    auto store_tile = [&]() {
        #pragma unroll
        for (int ch = 0; ch < CCH; ++ch)
            #pragma unroll
            for (int s = 0; s < 5; ++s) {
                const int idx = tid + 256 * s;    // imm-offset ds_write
                if (s < 4 || idx < 1156) tile[ch * 1156 + idx] = v[ch][s];
            }
    };

    // +-s in SGPRs: exact (s = fmax(absmax,1e-8); -s = exact sign flip).
    const float sAbs = fmaxf(__uint_as_float(maxb[LIDX]), 1e-8f);
    const float sPos = __uint_as_float(__builtin_amdgcn_readfirstlane(__float_as_uint(sAbs)));
    const float sNeg = __uint_as_float(__builtin_amdgcn_readfirstlane(__float_as_uint(-sAbs)));

    float acc[16][4];
    #pragma unroll
    for (int c = 0; c < 16; ++c)
        #pragma unroll
        for (int q = 0; q < 4; ++q) acc[c][q] = 0.f;

    const int base = (2 * ty) * 34 + 2 * tx;     // lane's patch origin (words)

    load_chunk(0);                                // prologue

    #pragma unroll 1
    for (int chunk = 0; chunk < NCHUNK; ++chunk) {
        // Issue header loads FIRST: uniform address -> s_load; latency
        // hides behind the staging barriers below.
        const unsigned* hdr = hdrs + (size_t)(grp * NCHUNK + chunk) * 36;
        unsigned cntd[4];
        #pragma unroll
        for (int i = 0; i < 4; ++i) cntd[i] = hdr[i];
        unsigned ent[32];
        #pragma unroll
        for (int i = 0; i < 32; ++i) ent[i] = hdr[4 + i];

        __syncthreads();                          // sync1: tile free; drains
                                                  // the (aged) prefetch
        store_tile();                             // v -> tile
        __syncthreads();                          // sync2: writes visible
        if (chunk + 1 < NCHUNK) load_chunk((chunk + 1) * 4);
        // ^ issued AFTER sync2 (isolated R23 ingredient): the cold loads
        //   age through the whole compute phase instead of being
        //   vmcnt(0)-drained immediately at sync2.

        const float* tb = tile + base;

        #pragma unroll
        for (int c = 0; c < 16; ++c) {
            const unsigned cnt = (cntd[c >> 2] >> ((c & 3) * 8)) & 0xffu;
            if (!cnt) continue;                   // uniform skip (~60% of co)
            #pragma unroll
            for (int j = 0; j < 4; ++j) {
                if ((int)cnt > j) {
                    const unsigned e = (ent[2 * c + (j >> 1)] >> ((j & 1) * 16)) & 0xffffu;
                    const float wv = (e & 0x8000u) ? sNeg : sPos;   // s_cselect
                    const float* q = tb + (e & 0x7fffu);            // v_add
                    acc[c][0] = fmaf(wv, q[0],  acc[c][0]);
                    acc[c][1] = fmaf(wv, q[1],  acc[c][1]);
                    acc[c][2] = fmaf(wv, q[34], acc[c][2]);
                    acc[c][3] = fmaf(wv, q[35], acc[c][3]);
                }
            }
            if (cnt > 4) {                        // rare (~1% of co)
                const unsigned short* pp =
                    pool + ((size_t)(grp * NCHUNK + chunk) * 16 + c) * 32;
                #pragma unroll 1
                for (int j = 4; j < (int)cnt; ++j) {
                    const unsigned e = pp[j - 4];
                    const float wv = (e & 0x8000u) ? sNeg : sPos;
                    const float* q = tb + (e & 0x7fffu);
                    acc[c][0] = fmaf(wv, q[0],  acc[c][0]);
                    acc[c][1] = fmaf(wv, q[1],  acc[c][1]);
                    acc[c][2] = fmaf(wv, q[34], acc[c][2]);
                    acc[c][3] = fmaf(wv, q[35], acc[c][3]);
                }
            }
        }
    }

    if constexpr (LIDX == 2) {
        // Fused global-max epilogue: out == g[32][128]. Values >= 0; max is
        // order-independent bit-exact; invalid threads contribute 0.0.
        const float alpha = *alpha_p;
        const float scale = alpha / 3.0f;         // 2^ABITS - 1 = 3
        const bool valid = (py < PH) && (px < PW);
        float mv[16];
        #pragma unroll
        for (int c = 0; c < 16; ++c) {
            const float m = fmaxf(fmaxf(acc[c][0], acc[c][1]),
                                  fmaxf(acc[c][2], acc[c][3]));
            const float y = fminf(fmaxf(m, 0.f), alpha);
            const float q = rintf(y / scale) * scale;
            mv[c] = valid ? q : 0.f;
        }
        #pragma unroll
        for (int c = 0; c < 16; ++c)
            #pragma unroll
            for (int o = 32; o > 0; o >>= 1)
                mv[c] = fmaxf(mv[c], __shfl_down(mv[c], o));
        __shared__ float red[4][16];
        const int lane = tid & 63, wv = tid >> 6;
        if (lane == 0) {
            #pragma unroll
            for (int c = 0; c < 16; ++c) red[wv][c] = mv[c];
        }
        __syncthreads();
        if (tid < 16) {
            const float r = fmaxf(fmaxf(red[0][tid], red[1][tid]),
                                  fmaxf(red[2][tid], red[3][tid]));
            atomicMax((unsigned*)(out + (size_t)b * 128 + grp * 16 + tid),
                      __float_as_uint(r));        // >=0: uint order == float
        }
    } else if (py < PH && px < PW) {
        const float alpha = *alpha_p;
        const float scale = alpha / 3.0f;         // 2^ABITS - 1 = 3
        #pragma unroll
        for (int c = 0; c < 16; ++c) {
            const float m = fmaxf(fmaxf(acc[c][0], acc[c][1]),
                                  fmaxf(acc[c][2], acc[c][3]));
            const float y = fminf(fmaxf(m, 0.f), alpha);
            out[(((size_t)b * Co + grp * 16 + c) * PH + py) * PW + px] =
                rintf(y / scale) * scale;
        }
    }
}

// 1x1 conv 128->10 per batch (same k-ascending FMA order as round 1).
__global__ __launch_bounds__(128)
void classify_kernel(const float* __restrict__ g, const float* __restrict__ qwc,
                     float* __restrict__ out) {
    const int b = blockIdx.x;
    __shared__ float gg[128];
    gg[threadIdx.x] = g[b * 128 + threadIdx.x];
    __syncthreads();
    if (threadIdx.x < 10) {
        float s = 0.f;
        for (int k = 0; k < 128; ++k) s += qwc[threadIdx.x * 128 + k] * gg[k];
        out[b * 10 + threadIdx.x] = s;
    }
}

extern "C" void kernel_launch(void* const* d_in, const int* in_sizes, int n_in,
                              void* d_out, int out_size, void* d_ws, size_t ws_size,
                              hipStream_t stream) {
    const float* x  = (const float*)d_in[0];
    const float* w1 = (const float*)d_in[1];
    const float* w2 = (const float*)d_in[2];
    const float* w3 = (const float*)d_in[3];
    const float* wc = (const float*)d_in[4];
    const float* a1 = (const float*)d_in[5];
    const float* a2 = (const float*)d_in[6];
    const float* a3 = (const float*)d_in[7];

    float* ws = (float*)d_ws;
    size_t o = 0;
    float*    qwc  = ws + o; o += 1280;
    unsigned* maxb = (unsigned*)(ws + o); o += 4;
    float*    g    = ws + o; o += 32 * 128;
    unsigned*       h1 = (unsigned*)(ws + o);       o += 2   * 36;   // hdrs
    unsigned short* p1 = (unsigned short*)(ws + o); o += 2   * 16 * 16;  // 32 hw/co
    unsigned*       h2 = (unsigned*)(ws + o);       o += 32  * 36;
    unsigned short* p2 = (unsigned short*)(ws + o); o += 32  * 16 * 16;
    unsigned*       h3 = (unsigned*)(ws + o);       o += 128 * 36;
    unsigned short* p3 = (unsigned short*)(ws + o); o += 128 * 16 * 16;
    float* h1p = ws + o; o += (size_t)32 * 32 * 112 * 112;
    float* h2p = ws + o; o += (size_t)32 * 64 * 56 * 56;

    prep_zero<<<16, 256, 0, stream>>>(maxb, g);
    prep_absmax<<<dim3(16, 4), 256, 0, stream>>>(w1, w2, w3, wc, maxb);
    build_lists<<<dim3(8, 4), 256, 0, stream>>>(w1, w2, w3, wc, maxb,
                                                h1, p1, h2, p2, h3, p3, qwc);

    // conv1: 3->32, 224x224 -> pooled 112x112. tiles 7x7, z = 32b * 2 grp
    conv_sparse<3, 32, 0><<<dim3(7, 7, 32 * 2), dim3(16, 16), 0, stream>>>(
        x, h1, p1, maxb, a1, h1p, 224, 224);
    // conv2: 32->64, pooled 56x56. tiles 4x4, z = 32b * 4 grp
    conv_sparse<32, 64, 1><<<dim3(4, 4, 32 * 4), dim3(16, 16), 0, stream>>>(
        h1p, h2, p2, maxb, a2, h2p, 112, 112);
    // conv3: 64->128, pooled 28x28, FUSED global-max -> g. tiles 2x2.
    conv_sparse<64, 128, 2><<<dim3(2, 2, 32 * 8), dim3(16, 16), 0, stream>>>(
        h2p, h3, p3, maxb, a3, g, 56, 56);

    classify_kernel<<<32, 128, 0, stream>>>(g, qwc, (float*)d_out);
}